// Round 4
// baseline (131.077 us; speedup 1.0000x reference)
//
#include <hip/hip_runtime.h>

// StructureTensorEffect: B=4, C=3, H=W=1024, fp32.
// Round 10: wide tiles for DRAM-pattern efficiency. Four structurally
// different versions (R3 no-LDS streaming, R7 3-phase LDS, R8 single-shot
// async LDS, R9 border-first) ALL land at 42-44us. Staging structure,
// barriers, block lifetime, dispatch order: none matter. Per-pipe math:
// VALU 9us (matches VALUBusy 21% x 42us), LDS 3us, HBM-at-peak 16us ->
// ~22us of unexplained memory-system loss. The invariant across all four:
// global reads are 288B row-chunks at 4KB stride (64-col tiles, 72-float
// staged rows); fills in the same trace stream contiguous at 6.2TB/s.
// Theory: short-chunk strided streams run DRAM/L2 at ~35% efficiency;
// chunk length is the controlling variable. This round: retile 64x32 ->
// 256x8. Per-thread work identical (1 col x 8 rows, same verified window
// algebra); staged row chunk becomes 264 floats = 1056B contiguous (4x);
// stores 1KB/row/plane. Cost: halo ratio 1.19 -> 1.25-1.75 (FETCH ~50 ->
// ~75MB) - positive trade iff pattern theory holds. Falsifier: dur
// unchanged with FETCH up => chunk length not the lever.
// Staging (R8): all 3 channels at once via global_load_lds (16B/lane,
// LDS linear in group idx = wave-uniform base + lane*16; per-lane clamped
// GLOBAL address does border replication), one vmcnt(0)+barrier, then
// all-channel compute, no further barriers. LDS 3*14*264*4 = 44352B.
// Borders: R4-proven scheme (store mask + border slice, dispatched first).

#define W_ 1024
#define H_ 1024
#define PLANE (1 << 20)
#define TCOLS 256
#define TROWS 8
#define ROWS 8
#define LSTRIDE 264    // staged cols: x0-4 .. x0+259 (66 float4 groups)
#define GPR 66         // float4 groups per staged row

__device__ __forceinline__ float lerp1(float a, float b, float f) {
    return fmaf(f, b - a, a);
}

// async 16B global->LDS copy (gfx950). Dest must be linear in lane order.
__device__ __forceinline__ void async_copy16(const float* g, float* s) {
    __builtin_amdgcn_global_load_lds(
        (const __attribute__((address_space(1))) unsigned int*)g,
        (__attribute__((address_space(3))) unsigned int*)s,
        16, 0, 0);
}

// Exact per-pixel reference path (any sigma, any border) — verified R1-R9.
__device__ void slow_pixel(const float* __restrict__ Xb, float* __restrict__ Ob,
                           float sg, int xi, int y)
{
    float imf = floorf(-sg), ipf = floorf(sg);
    float fm  = -sg - imf;
    float fp  =  sg - ipf;
    int   im  = (int)imf, ip = (int)ipf;

    int cm0 = min(max(xi + im, 0), W_ - 1), cm1 = min(cm0 + 1, W_ - 1);
    int cp0 = min(max(xi + ip, 0), W_ - 1), cp1 = min(cp0 + 1, W_ - 1);
    int rm0 = min(max(y + im, 0), H_ - 1),  rm1 = min(rm0 + 1, H_ - 1);
    int rp0 = min(max(y + ip, 0), H_ - 1),  rp1 = min(rp0 + 1, H_ - 1);

    int o_rm0 = rm0 << 10, o_rm1 = rm1 << 10;
    int o_rp0 = rp0 << 10, o_rp1 = rp1 << 10;
    int o_r0  = y   << 10;

    float oxx = 0.f, oyy = 0.f, oxy = 0.f;

    #pragma unroll
    for (int c = 0; c < 3; ++c) {
        const float* base = Xb + ((size_t)c << 20);

        float hm_m0 = lerp1(base[o_rm0 + cm0], base[o_rm0 + cm1], fm);
        float hm_m1 = lerp1(base[o_rm1 + cm0], base[o_rm1 + cm1], fm);
        float hm_0  = lerp1(base[o_r0  + cm0], base[o_r0  + cm1], fm);
        float hm_p0 = lerp1(base[o_rp0 + cm0], base[o_rp0 + cm1], fm);
        float hm_p1 = lerp1(base[o_rp1 + cm0], base[o_rp1 + cm1], fm);
        float hp_m0 = lerp1(base[o_rm0 + cp0], base[o_rm0 + cp1], fp);
        float hp_m1 = lerp1(base[o_rm1 + cp0], base[o_rm1 + cp1], fp);
        float hp_0  = lerp1(base[o_r0  + cp0], base[o_r0  + cp1], fp);
        float hp_p0 = lerp1(base[o_rp0 + cp0], base[o_rp0 + cp1], fp);
        float hp_p1 = lerp1(base[o_rp1 + cp0], base[o_rp1 + cp1], fp);
        float h0_m0 = base[o_rm0 + xi], h0_m1 = base[o_rm1 + xi];
        float h0_p0 = base[o_rp0 + xi], h0_p1 = base[o_rp1 + xi];

        float t0 = lerp1(hm_m0, hm_m1, fm);
        float t1 = hm_0;
        float t2 = lerp1(hm_p0, hm_p1, fp);
        float t3 = lerp1(h0_m0, h0_m1, fm);
        float t4 = lerp1(h0_p0, h0_p1, fp);
        float t5 = lerp1(hp_m0, hp_m1, fm);
        float t6 = hp_0;
        float t7 = lerp1(hp_p0, hp_p1, fp);

        float su = 0.25f * (t5 + t7 - t0 - t2) + 0.5f * (t6 - t1);
        float sv = 0.25f * (t2 + t7 - t0 - t5) + 0.5f * (t4 - t3);

        float l2 = (c == 0) ? 10000.f : 1.f;
        oxx = fmaf(l2 * su, su, oxx);
        oyy = fmaf(l2 * sv, sv, oyy);
        oxy = fmaf(l2 * su, sv, oxy);
    }

    int pix = (y << 10) | xi;
    Ob[pix]             = oxx;
    Ob[PLANE + pix]     = oyy;
    Ob[2 * PLANE + pix] = oxy;
}

template<int N>
__device__ __forceinline__ void acc(float (&arr)[N], int k, float val) {
    if (k >= 0 && k < N) arr[k] += val;   // k constant after unroll
}

// Fast tile: block covers cols x0..x0+255, rows y0..y0+7 (1 col/thread).
// Stage ALL channels' clamped windows (rows y0-IP-1..y0+8+IP, cols
// x0-4..x0+259) into LDS via async 16B copies, one barrier, then stream
// the accumulate from LDS for all 3 channels with no further barriers.
// Store mask (x>IP && x<1023-IP && y>IP) excludes clamp-wrong px; those
// are covered by the border slice.
template<int IP>
__device__ void fast_tile(const float* __restrict__ Xb, float* __restrict__ Ob,
                          float fp, float fm, int x0, int y0,
                          int tx, float* smem)
{
    constexpr int LROWS  = TROWS + 2 * IP + 2;   // staged rows per channel
    constexpr int RW     = ROWS + 2 * IP + 2;    // window rows per thread
    constexpr int NG     = 3 * LROWS * GPR;      // float4 groups, all channels
    constexpr int FULLIT = NG / 256;             // guard-free iterations

    int x = x0 + tx;

    auto stage = [&](int g) {
        int row  = g / GPR;            // 0 .. 3*LROWS-1
        int grp  = g - row * GPR;
        int c    = row / LROWS;
        int lrow = row - c * LROWS;
        int gr   = min(max(y0 - IP - 1 + lrow, 0), H_ - 1);
        int gc   = min(max(x0 - 4 + grp * 4, 0), W_ - 4);
        async_copy16(Xb + ((size_t)c << 20) + (gr << 10) + gc,
                     smem + g * 4);    // LDS linear in g: lane-contiguous
    };

    // ---- single-shot staging: all channels, direct-to-LDS ----
    #pragma unroll
    for (int it = 0; it < FULLIT; ++it)
        stage(it * 256 + tx);          // uniform exec
    if (FULLIT * 256 + tx < NG)        // single guarded tail copy
        stage(FULLIT * 256 + tx);

    __syncthreads();   // compiler emits vmcnt(0) drain before s_barrier

    float oxx[ROWS], oyy[ROWS], oxy[ROWS];
    #pragma unroll
    for (int k = 0; k < ROWS; ++k) { oxx[k] = 0.f; oyy[k] = 0.f; oxy[k] = 0.f; }

    // thread's LDS read base: window row w of channel c lives at LDS row
    // c*LROWS + w; LDS col of global col gcol is gcol-(x0-4); a0 is at
    // col x-IP-1 -> tx + 3 - IP.
    const float* spb = smem + tx + (3 - IP);

    #pragma unroll
    for (int c = 0; c < 3; ++c) {
        const float* sp = spb + c * (LROWS * LSTRIDE);

        float su[ROWS], sv[ROWS];
        #pragma unroll
        for (int k = 0; k < ROWS; ++k) { su[k] = 0.f; sv[k] = 0.f; }

        #pragma unroll
        for (int w = 0; w < RW; ++w) {
            float a0 = sp[w * LSTRIDE];
            float a1 = sp[w * LSTRIDE + 1];
            float cc = sp[w * LSTRIDE + IP + 1];
            float b0 = sp[w * LSTRIDE + 2 * IP + 1];
            float b1 = sp[w * LSTRIDE + 2 * IP + 2];
            float hm = lerp1(a0, a1, fm);
            float hp = lerp1(b0, b1, fp);
            float q  = hp - hm;
            float A  = 0.25f * q;
            float hq = 0.5f  * q;
            float Bv = fmaf(0.25f, hm + hp, 0.5f * cc);
            float fpA = fp * A,  fmA = fm * A;
            float fpB = fp * Bv, fmB = fm * Bv;

            acc(su, w,              fpA);
            acc(su, w - 1,          fmA);
            acc(su, w - IP - 1,     hq);
            acc(su, w - 2*IP - 1,   fmA);
            acc(su, w - 2*IP - 2,   fpA);
            acc(sv, w,             -fpB);
            acc(sv, w - 1,         -fmB);
            acc(sv, w - 2*IP - 1,   fmB);
            acc(sv, w - 2*IP - 2,   fpB);
        }

        float l2 = (c == 0) ? 10000.f : 1.f;
        #pragma unroll
        for (int k = 0; k < ROWS; ++k) {
            oxx[k] = fmaf(l2 * su[k], su[k], oxx[k]);
            oyy[k] = fmaf(l2 * sv[k], sv[k], oyy[k]);
            oxy[k] = fmaf(l2 * su[k], sv[k], oxy[k]);
        }
    }

    bool okx = (x > IP) && (x < W_ - 1 - IP);
    #pragma unroll
    for (int k = 0; k < ROWS; ++k) {
        int y = y0 + k;
        if (okx && y > IP) {
            int pix = (y << 10) | x;
            Ob[pix]             = oxx[k];
            Ob[PLANE + pix]     = oyy[k];
            Ob[2 * PLANE + pix] = oxy[k];
        }
    }
}

// block (256,1). grid = (4, 129, 4): y==0 border slice (first), then 128
// 8-row bands.
__global__ __launch_bounds__(256) void st_kernel(
    const float* __restrict__ X, const float* __restrict__ S,
    float* __restrict__ O)
{
    int b  = blockIdx.z;
    const float* Xb = X + (size_t)b * 3 * PLANE;
    float*       Ob = O + (size_t)b * 3 * PLANE;
    float sg = S[b];

    int tx = threadIdx.x;

    if (blockIdx.y == 0) {
        // Border slice, dispatched first so its gather-heavy blocks
        // overlap under the fast-tile phase. x in {0,1,2,1021,1022,1023}
        // all y (6144 px) plus y in {0,1,2} all x (3072 px).
        // 4 blocks * 256 = 1024 threads -> 9 iters.
        int t = blockIdx.x * 256 + tx;
        #pragma unroll
        for (int it = 0; it < 9; ++it) {
            int pidx = t + it * 1024;
            if (pidx < 6144) {
                int yy = pidx / 6;
                int cc = pidx - yy * 6;
                int xx = (cc < 3) ? cc : (W_ - 6 + cc);
                slow_pixel(Xb, Ob, sg, xx, yy);
            } else if (pidx < 9216) {
                int p2 = pidx - 6144;
                slow_pixel(Xb, Ob, sg, p2 & 1023, p2 >> 10);
            }
        }
        return;
    }

    int x0 = blockIdx.x * TCOLS;
    int y0 = (blockIdx.y - 1) * TROWS;

    int ipv = (int)floorf(sg);
    int imv = (int)floorf(-sg);
    bool sig_ok = (imv == -ipv - 1) && ipv >= 0 && ipv <= 2;  // block-uniform
    float fp = sg - (float)ipv;
    float fm = 1.0f - fp;

    // worst case IP=2: 3 channels x 14 rows x 264 cols = 44352 B -> 3 blk/CU
    __shared__ float smem[3 * (TROWS + 6) * LSTRIDE];

    if (sig_ok) {
        switch (ipv) {
            case 0:  fast_tile<0>(Xb, Ob, fp, fm, x0, y0, tx, smem); break;
            case 1:  fast_tile<1>(Xb, Ob, fp, fm, x0, y0, tx, smem); break;
            default: fast_tile<2>(Xb, Ob, fp, fm, x0, y0, tx, smem); break;
        }
    } else {
        for (int k = 0; k < ROWS; ++k)
            slow_pixel(Xb, Ob, sg, x0 + tx, y0 + k);
    }
}

extern "C" void kernel_launch(void* const* d_in, const int* in_sizes, int n_in,
                              void* d_out, int out_size, void* d_ws, size_t ws_size,
                              hipStream_t stream) {
    const float* x     = (const float*)d_in[0];
    const float* sigma = (const float*)d_in[1];
    float* out = (float*)d_out;

    dim3 grid(W_ / TCOLS, H_ / TROWS + 1, 4), block(256, 1);
    hipLaunchKernelGGL(st_kernel, grid, block, 0, stream, x, sigma, out);
}

// Round 5
// 116.798 us; speedup vs baseline: 1.1223x; 1.1223x over previous
//
#include <hip/hip_runtime.h>

// StructureTensorEffect: B=4, C=3, H=W=1024, fp32.
// Round 11: wide-wave-store epilogue. Evidence so far: R3/R7/R8/R9 (four
// different read/staging structures) all ~42-44us; R10 (wide tiles) got
// FETCH down to 42MB yet ran 58.6us, and cold (HBM reads) vs warm (reads
// L3-absorbed) dispatches time IDENTICALLY -> reads are irrelevant.
// OccupancyPercent is unreliable on gfx950 (fill kernel shows 8.4% occ at
// 78% BW peak) -> discard occupancy reasoning. Pipe accounting (VALU 9us,
// LDS 3us, writes-at-peak 8us) leaves ~30us unexplained. The ONE element
// never varied across all rounds: the epilogue writes 24 scattered 256B
// wave-segments (dword/lane, 3 planes x 4MB stride). The harness fill
// writes the same buffer contiguously (dwordx4) at 6.2 TB/s. This round
// keeps R10's staging+compute verbatim and changes ONLY the epilogue:
// results bounce through reused LDS, then cooperative float4 stores --
// 1KB contiguous per wave-instruction (fill-kernel pattern). Also
// restores border parallelism (2 grid rows, 8 blocks/batch, 5 iters vs
// R10's 9) to undo R10's independent border regression.
// Staging (R8/R10): all 3 channels at once via global_load_lds (16B/lane,
// LDS linear in group idx = wave-uniform base + lane*16; per-lane clamped
// GLOBAL address does border replication), one vmcnt(0)+barrier, then
// all-channel compute, no further barriers. LDS 3*14*264*4 = 44352B.
// Borders: R4-proven scheme (store mask + border slice, dispatched first).

#define W_ 1024
#define H_ 1024
#define PLANE (1 << 20)
#define TCOLS 256
#define TROWS 8
#define ROWS 8
#define LSTRIDE 264    // staged cols: x0-4 .. x0+259 (66 float4 groups)
#define GPR 66         // float4 groups per staged row

__device__ __forceinline__ float lerp1(float a, float b, float f) {
    return fmaf(f, b - a, a);
}

// async 16B global->LDS copy (gfx950). Dest must be linear in lane order.
__device__ __forceinline__ void async_copy16(const float* g, float* s) {
    __builtin_amdgcn_global_load_lds(
        (const __attribute__((address_space(1))) unsigned int*)g,
        (__attribute__((address_space(3))) unsigned int*)s,
        16, 0, 0);
}

// Exact per-pixel reference path (any sigma, any border) — verified R1-R10.
__device__ void slow_pixel(const float* __restrict__ Xb, float* __restrict__ Ob,
                           float sg, int xi, int y)
{
    float imf = floorf(-sg), ipf = floorf(sg);
    float fm  = -sg - imf;
    float fp  =  sg - ipf;
    int   im  = (int)imf, ip = (int)ipf;

    int cm0 = min(max(xi + im, 0), W_ - 1), cm1 = min(cm0 + 1, W_ - 1);
    int cp0 = min(max(xi + ip, 0), W_ - 1), cp1 = min(cp0 + 1, W_ - 1);
    int rm0 = min(max(y + im, 0), H_ - 1),  rm1 = min(rm0 + 1, H_ - 1);
    int rp0 = min(max(y + ip, 0), H_ - 1),  rp1 = min(rp0 + 1, H_ - 1);

    int o_rm0 = rm0 << 10, o_rm1 = rm1 << 10;
    int o_rp0 = rp0 << 10, o_rp1 = rp1 << 10;
    int o_r0  = y   << 10;

    float oxx = 0.f, oyy = 0.f, oxy = 0.f;

    #pragma unroll
    for (int c = 0; c < 3; ++c) {
        const float* base = Xb + ((size_t)c << 20);

        float hm_m0 = lerp1(base[o_rm0 + cm0], base[o_rm0 + cm1], fm);
        float hm_m1 = lerp1(base[o_rm1 + cm0], base[o_rm1 + cm1], fm);
        float hm_0  = lerp1(base[o_r0  + cm0], base[o_r0  + cm1], fm);
        float hm_p0 = lerp1(base[o_rp0 + cm0], base[o_rp0 + cm1], fm);
        float hm_p1 = lerp1(base[o_rp1 + cm0], base[o_rp1 + cm1], fm);
        float hp_m0 = lerp1(base[o_rm0 + cp0], base[o_rm0 + cp1], fp);
        float hp_m1 = lerp1(base[o_rm1 + cp0], base[o_rm1 + cp1], fp);
        float hp_0  = lerp1(base[o_r0  + cp0], base[o_r0  + cp1], fp);
        float hp_p0 = lerp1(base[o_rp0 + cp0], base[o_rp0 + cp1], fp);
        float hp_p1 = lerp1(base[o_rp1 + cp0], base[o_rp1 + cp1], fp);
        float h0_m0 = base[o_rm0 + xi], h0_m1 = base[o_rm1 + xi];
        float h0_p0 = base[o_rp0 + xi], h0_p1 = base[o_rp1 + xi];

        float t0 = lerp1(hm_m0, hm_m1, fm);
        float t1 = hm_0;
        float t2 = lerp1(hm_p0, hm_p1, fp);
        float t3 = lerp1(h0_m0, h0_m1, fm);
        float t4 = lerp1(h0_p0, h0_p1, fp);
        float t5 = lerp1(hp_m0, hp_m1, fm);
        float t6 = hp_0;
        float t7 = lerp1(hp_p0, hp_p1, fp);

        float su = 0.25f * (t5 + t7 - t0 - t2) + 0.5f * (t6 - t1);
        float sv = 0.25f * (t2 + t7 - t0 - t5) + 0.5f * (t4 - t3);

        float l2 = (c == 0) ? 10000.f : 1.f;
        oxx = fmaf(l2 * su, su, oxx);
        oyy = fmaf(l2 * sv, sv, oyy);
        oxy = fmaf(l2 * su, sv, oxy);
    }

    int pix = (y << 10) | xi;
    Ob[pix]             = oxx;
    Ob[PLANE + pix]     = oyy;
    Ob[2 * PLANE + pix] = oxy;
}

template<int N>
__device__ __forceinline__ void acc(float (&arr)[N], int k, float val) {
    if (k >= 0 && k < N) arr[k] += val;   // k constant after unroll
}

// Fast tile: block covers cols x0..x0+255, rows y0..y0+7 (1 col/thread).
// Stage -> compute identical to R10. Epilogue: results bounce through
// reused LDS, then cooperative float4 stores (1KB contiguous per wave).
// Edge float4s (first/last x-tile, first band) decompose to masked dword
// stores; masked-out px are covered by the border slice.
template<int IP>
__device__ void fast_tile(const float* __restrict__ Xb, float* __restrict__ Ob,
                          float fp, float fm, int x0, int y0,
                          int tx, float* smem)
{
    constexpr int LROWS  = TROWS + 2 * IP + 2;   // staged rows per channel
    constexpr int RW     = ROWS + 2 * IP + 2;    // window rows per thread
    constexpr int NG     = 3 * LROWS * GPR;      // float4 groups, all channels
    constexpr int FULLIT = NG / 256;             // guard-free iterations

    int x = x0 + tx;

    auto stage = [&](int g) {
        int row  = g / GPR;            // 0 .. 3*LROWS-1
        int grp  = g - row * GPR;
        int c    = row / LROWS;
        int lrow = row - c * LROWS;
        int gr   = min(max(y0 - IP - 1 + lrow, 0), H_ - 1);
        int gc   = min(max(x0 - 4 + grp * 4, 0), W_ - 4);
        async_copy16(Xb + ((size_t)c << 20) + (gr << 10) + gc,
                     smem + g * 4);    // LDS linear in g: lane-contiguous
    };

    // ---- single-shot staging: all channels, direct-to-LDS ----
    #pragma unroll
    for (int it = 0; it < FULLIT; ++it)
        stage(it * 256 + tx);          // uniform exec
    if (FULLIT * 256 + tx < NG)        // single guarded tail copy
        stage(FULLIT * 256 + tx);

    __syncthreads();   // compiler emits vmcnt(0) drain before s_barrier

    float oxx[ROWS], oyy[ROWS], oxy[ROWS];
    #pragma unroll
    for (int k = 0; k < ROWS; ++k) { oxx[k] = 0.f; oyy[k] = 0.f; oxy[k] = 0.f; }

    // thread's LDS read base: window row w of channel c lives at LDS row
    // c*LROWS + w; LDS col of global col gcol is gcol-(x0-4); a0 is at
    // col x-IP-1 -> tx + 3 - IP.
    const float* spb = smem + tx + (3 - IP);

    #pragma unroll
    for (int c = 0; c < 3; ++c) {
        const float* sp = spb + c * (LROWS * LSTRIDE);

        float su[ROWS], sv[ROWS];
        #pragma unroll
        for (int k = 0; k < ROWS; ++k) { su[k] = 0.f; sv[k] = 0.f; }

        #pragma unroll
        for (int w = 0; w < RW; ++w) {
            float a0 = sp[w * LSTRIDE];
            float a1 = sp[w * LSTRIDE + 1];
            float cc = sp[w * LSTRIDE + IP + 1];
            float b0 = sp[w * LSTRIDE + 2 * IP + 1];
            float b1 = sp[w * LSTRIDE + 2 * IP + 2];
            float hm = lerp1(a0, a1, fm);
            float hp = lerp1(b0, b1, fp);
            float q  = hp - hm;
            float A  = 0.25f * q;
            float hq = 0.5f  * q;
            float Bv = fmaf(0.25f, hm + hp, 0.5f * cc);
            float fpA = fp * A,  fmA = fm * A;
            float fpB = fp * Bv, fmB = fm * Bv;

            acc(su, w,              fpA);
            acc(su, w - 1,          fmA);
            acc(su, w - IP - 1,     hq);
            acc(su, w - 2*IP - 1,   fmA);
            acc(su, w - 2*IP - 2,   fpA);
            acc(sv, w,             -fpB);
            acc(sv, w - 1,         -fmB);
            acc(sv, w - 2*IP - 1,   fmB);
            acc(sv, w - 2*IP - 2,   fpB);
        }

        float l2 = (c == 0) ? 10000.f : 1.f;
        #pragma unroll
        for (int k = 0; k < ROWS; ++k) {
            oxx[k] = fmaf(l2 * su[k], su[k], oxx[k]);
            oyy[k] = fmaf(l2 * sv[k], sv[k], oyy[k]);
            oxy[k] = fmaf(l2 * su[k], sv[k], oxy[k]);
        }
    }

    // ---- wide-store epilogue: LDS transpose -> 1KB/wave float4 stores ----
    __syncthreads();   // all LDS window reads done; reuse smem
    #pragma unroll
    for (int k = 0; k < ROWS; ++k) {
        smem[           (k << 8) + tx] = oxx[k];
        smem[2048 +     (k << 8) + tx] = oyy[k];
        smem[4096 +     (k << 8) + tx] = oxy[k];
    }
    __syncthreads();

    // 3 planes x 8 rows x 256 cols = 1536 float4s; 6 per thread.
    // idx lane-consecutive -> 64 lanes cover 1KB contiguous per store.
    const float4* sm4 = reinterpret_cast<const float4*>(smem);
    bool xedge_lo = (x0 == 0);
    bool xedge_hi = (x0 == W_ - TCOLS);
    #pragma unroll
    for (int j = 0; j < 6; ++j) {
        int idx = (j << 8) + tx;           // 0..1535
        int p   = idx >> 9;                // plane
        int rem = idx & 511;
        int r   = rem >> 6;                // row in band
        int c4  = rem & 63;                // float4 col group
        int y   = y0 + r;
        int xg  = x0 + (c4 << 2);
        float4 v = sm4[idx];
        bool f4ok = (y > IP) && !(xedge_lo && c4 == 0) && !(xedge_hi && c4 == 63);
        float* dst = Ob + (size_t)p * PLANE + (y << 10) + xg;
        if (f4ok) {
            *reinterpret_cast<float4*>(dst) = v;
        } else if (y > IP) {
            // decompose: per-dword mask at x-edges
            float vv[4] = {v.x, v.y, v.z, v.w};
            #pragma unroll
            for (int d = 0; d < 4; ++d) {
                int xx = xg + d;
                if (xx > IP && xx < W_ - 1 - IP) dst[d] = vv[d];
            }
        }
    }
}

// block (256,1). grid = (4, 130, 4): y in {0,1} border slice (first),
// then 128 8-row bands.
__global__ __launch_bounds__(256) void st_kernel(
    const float* __restrict__ X, const float* __restrict__ S,
    float* __restrict__ O)
{
    int b  = blockIdx.z;
    const float* Xb = X + (size_t)b * 3 * PLANE;
    float*       Ob = O + (size_t)b * 3 * PLANE;
    float sg = S[b];

    int tx = threadIdx.x;

    if (blockIdx.y < 2) {
        // Border slice, dispatched first so its gather-heavy blocks
        // overlap under the fast-tile phase. x in {0,1,2,1021,1022,1023}
        // all y (6144 px) plus y in {0,1,2} all x (3072 px).
        // 8 blocks * 256 = 2048 threads -> 5 iters.
        int t = (blockIdx.y * gridDim.x + blockIdx.x) * 256 + tx;
        #pragma unroll
        for (int it = 0; it < 5; ++it) {
            int pidx = t + it * 2048;
            if (pidx < 6144) {
                int yy = pidx / 6;
                int cc = pidx - yy * 6;
                int xx = (cc < 3) ? cc : (W_ - 6 + cc);
                slow_pixel(Xb, Ob, sg, xx, yy);
            } else if (pidx < 9216) {
                int p2 = pidx - 6144;
                slow_pixel(Xb, Ob, sg, p2 & 1023, p2 >> 10);
            }
        }
        return;
    }

    int x0 = blockIdx.x * TCOLS;
    int y0 = (blockIdx.y - 2) * TROWS;

    int ipv = (int)floorf(sg);
    int imv = (int)floorf(-sg);
    bool sig_ok = (imv == -ipv - 1) && ipv >= 0 && ipv <= 2;  // block-uniform
    float fp = sg - (float)ipv;
    float fm = 1.0f - fp;

    // worst case IP=2: 3 ch x 14 rows x 264 cols = 44352 B (store area
    // 24576B reuses it) -> 3 blk/CU
    __shared__ __align__(16) float smem[3 * (TROWS + 6) * LSTRIDE];

    if (sig_ok) {
        switch (ipv) {
            case 0:  fast_tile<0>(Xb, Ob, fp, fm, x0, y0, tx, smem); break;
            case 1:  fast_tile<1>(Xb, Ob, fp, fm, x0, y0, tx, smem); break;
            default: fast_tile<2>(Xb, Ob, fp, fm, x0, y0, tx, smem); break;
        }
    } else {
        for (int k = 0; k < ROWS; ++k)
            slow_pixel(Xb, Ob, sg, x0 + tx, y0 + k);
    }
}

extern "C" void kernel_launch(void* const* d_in, const int* in_sizes, int n_in,
                              void* d_out, int out_size, void* d_ws, size_t ws_size,
                              hipStream_t stream) {
    const float* x     = (const float*)d_in[0];
    const float* sigma = (const float*)d_in[1];
    float* out = (float*)d_out;

    dim3 grid(W_ / TCOLS, H_ / TROWS + 2, 4), block(256, 1);
    hipLaunchKernelGGL(st_kernel, grid, block, 0, stream, x, sigma, out);
}